// Round 6
// baseline (104.075 us; speedup 1.0000x reference)
//
#include <hip/hip_runtime.h>
#include <hip/hip_bf16.h>

// MXFP8Linear: out[n,j] = sum_b sx[n,b]*sw[j,b]*dot32(fp8(x),fp8(w)) + bias[j]
// Strategy: qdq both matrices to bf16 with scales folded in, then bf16 MFMA
// GEMM (A * B^T, both K-contig).
// R6: 128x64 tile, 2 waves of 64x64 wave-tile (18.3 FLOP/LDS-byte vs 14.2),
// triple-buffered LDS (72KB, 2 blocks/CU), prefetch depth 2 with counted
// vmcnt(24) (loads get ~2 compute phases to land), XCD-swizzled grid.

typedef __attribute__((ext_vector_type(8))) __bf16 bf16x8;
typedef __attribute__((ext_vector_type(4))) float f32x4;

#define NMAT 2048
#define FP8_MAX 448.0f

__device__ inline unsigned short bfbits(float f) {
  union { __hip_bfloat16 h; unsigned short u; } cv;
  cv.h = __float2bfloat16(f);
  return cv.u;
}

// quantize a,b to fp8 e4m3 (HW RNE, OCP on gfx950), dequant, pack 2 bf16
__device__ inline unsigned pack2(float a, float b, float scale) {
  int p = __builtin_amdgcn_cvt_pk_fp8_f32(a / scale, b / scale, 0, false);
  float qa = __builtin_amdgcn_cvt_f32_fp8(p, 0) * scale;
  float qb = __builtin_amdgcn_cvt_f32_fp8(p, 1) * scale;
  return (unsigned)bfbits(qa) | ((unsigned)bfbits(qb) << 16);
}

// Coalesced qdq: lane loads float4 coalesced; 32-block = 8 consecutive lanes;
// amax via shfl_xor(1,2,4); 8B/lane coalesced store. One launch for x and w.
__global__ __launch_bounds__(256) void qdq_kernel(const float* __restrict__ x,
                                                  uint2* __restrict__ xo,
                                                  const float* __restrict__ w,
                                                  uint2* __restrict__ wo) {
  int g = blockIdx.x;
  const float* in;
  uint2* out;
  if (g >= 4096) { in = w; out = wo; g -= 4096; }
  else           { in = x; out = xo; }
  const int t = threadIdx.x;
  const size_t base = (size_t)g * 1024;  // floats per workgroup
  float4 v = ((const float4*)(in + base))[t];
  float amax = fmaxf(fmaxf(fabsf(v.x), fabsf(v.y)), fmaxf(fabsf(v.z), fabsf(v.w)));
  amax = fmaxf(amax, __shfl_xor(amax, 1));
  amax = fmaxf(amax, __shfl_xor(amax, 2));
  amax = fmaxf(amax, __shfl_xor(amax, 4));
  float scale = fmaxf(amax / FP8_MAX, 1e-30f);  // real div to match reference
  uint2 r;
  r.x = pack2(v.x, v.y, scale);
  r.y = pack2(v.z, v.w, scale);
  out[base / 4 + t] = r;
}

// C[n,j] = sum_k A[n,k]*B[j,k] + bias[j]
// BM=128 BN=64 BK=64; 128 threads = 2 waves, wave-tile 64x64 (4x4 16x16x32
// frags). LDS buf = A 16K + B 8K = 24K; 3 bufs = 72KB -> 2 blocks/CU.
// Pipeline: 2 tiles in flight; per tile {STAGE(t+2); vmcnt(24); bar;
// compute(t); bar} — counted vmcnt gives each tile's 12 loads ~2 phases.
// LDS swizzle: LDS[r][c ^ ((r&7)<<4)] = G[r][c]; staging pre-swizzles the
// GLOBAL source (global_load_lds dest must stay linear), reads apply the XOR.
__global__ __launch_bounds__(128, 1) void gemm_kernel(const __bf16* __restrict__ A,
                                                      const __bf16* __restrict__ B,
                                                      const float* __restrict__ bias,
                                                      float* __restrict__ C) {
  __shared__ __align__(16) char lds[73728];  // 3 x [A 16K | B 8K]
  const int tid  = threadIdx.x;
  const int lane = tid & 63;
  const int wid  = tid >> 6;   // 0..1 -> row offset wid*64

  // XCD-aware swizzle (512 WGs, 512%8==0 -> simple form is bijective)
  const int bid = blockIdx.x;
  const int swz = (bid & 7) * 64 + (bid >> 3);
  const int row0 = (swz >> 5) * 128;   // 16 row-tiles
  const int col0 = (swz & 31) * 64;    // 32 col-tiles

  // ---- staging: A = 8 issues, B = 4 issues (128 thr x 16B = 2KB each) ----
  // issue i covers linear tile bytes [i*2048,(i+1)*2048); rows are 128B.
  const char* AgS[8];
  const char* BgS[4];
#pragma unroll
  for (int i = 0; i < 8; ++i) {
    const int o = i * 2048 + tid * 16;
    const int r = o >> 7;
    const int c = (o & 127) ^ ((r & 7) << 4);  // pre-swizzled source col
    AgS[i] = (const char*)A + (size_t)(row0 + r) * 4096 + c;
    if (i < 4)
      BgS[i] = (const char*)B + (size_t)(col0 + r) * 4096 + c;
  }
  const int dst = tid * 16;

#define STAGE(buf, kt) do {                                                      \
    const int kb = (kt) * 128;                                                   \
    char* lb = lds + (buf) * 24576;                                              \
    _Pragma("unroll")                                                            \
    for (int i = 0; i < 8; ++i)                                                  \
      __builtin_amdgcn_global_load_lds(                                          \
          (const __attribute__((address_space(1))) unsigned*)(AgS[i] + kb),      \
          (__attribute__((address_space(3))) unsigned*)(lb + i * 2048 + dst),    \
          16, 0, 0);                                                             \
    _Pragma("unroll")                                                            \
    for (int j = 0; j < 4; ++j)                                                  \
      __builtin_amdgcn_global_load_lds(                                          \
          (const __attribute__((address_space(1))) unsigned*)(BgS[j] + kb),      \
          (__attribute__((address_space(3))) unsigned*)(lb + 16384 + j * 2048 + dst), \
          16, 0, 0);                                                             \
  } while (0)

#define WAITBAR(N) do {                                            \
    asm volatile("s_waitcnt vmcnt(" #N ")" ::: "memory");          \
    __builtin_amdgcn_sched_barrier(0);                             \
    __builtin_amdgcn_s_barrier();                                  \
  } while (0)
#define PBAR() do {                                                \
    __builtin_amdgcn_sched_barrier(0);                             \
    __builtin_amdgcn_s_barrier();                                  \
  } while (0)

  // ---- fragment read addressing (swizzled) ----
  const int l15 = lane & 15;
  const int q16 = (lane >> 4) * 16;        // 16B sub-chunk within 32-k step
  const int swb = (l15 & 7) << 4;          // row&7 == l15&7 (row offsets %8==0)
  const int ck0 = q16 ^ swb;               // kk=0 byte col (swizzled)
  const int ck1 = (64 + q16) ^ swb;        // kk=1
  const int aRow = (wid * 64 + l15) * 128; // byte row base for A frags
  const int bRow = l15 * 128;              // byte row base for B frags

  f32x4 acc[4][4] = {};

  auto compute = [&](const int buf) {
    const char* ab = lds + buf * 24576;
    const char* bb = ab + 16384;
    bf16x8 a0[4], a1[4], b0[4], b1[4];
#pragma unroll
    for (int m = 0; m < 4; ++m) {
      a0[m] = *(const bf16x8*)(ab + aRow + m * 2048 + ck0);
      a1[m] = *(const bf16x8*)(ab + aRow + m * 2048 + ck1);
    }
#pragma unroll
    for (int n = 0; n < 4; ++n) {
      b0[n] = *(const bf16x8*)(bb + bRow + n * 2048 + ck0);
      b1[n] = *(const bf16x8*)(bb + bRow + n * 2048 + ck1);
    }
#pragma unroll
    for (int m = 0; m < 4; ++m)
#pragma unroll
      for (int n = 0; n < 4; ++n) {
        acc[m][n] = __builtin_amdgcn_mfma_f32_16x16x32_bf16(a0[m], b0[n], acc[m][n], 0, 0, 0);
        acc[m][n] = __builtin_amdgcn_mfma_f32_16x16x32_bf16(a1[m], b1[n], acc[m][n], 0, 0, 0);
      }
  };

  STAGE(0, 0);
  STAGE(1, 1);
#pragma unroll 1
  for (int t = 0; t < 30; t += 3) {
    STAGE(2, t + 2);
    WAITBAR(24);          // tile t's 12 loads done; t+1,t+2 stay in flight
    compute(0);
    PBAR();               // all waves done reading buf0 before overwrite
    STAGE(0, t + 3);
    WAITBAR(24);
    compute(1);
    PBAR();
    STAGE(1, t + 4);
    WAITBAR(24);
    compute(2);
    PBAR();
  }
  // tiles 30 (buf0) and 31 (buf1) already staged and in flight
  WAITBAR(12);
  compute(0);             // tile 30
  PBAR();
  WAITBAR(0);
  compute(1);             // tile 31

  // epilogue: C/D layout col=lane&15, row=(lane>>4)*4+reg  [m89 verified]
  const int rb = row0 + wid * 64 + (lane >> 4) * 4;
#pragma unroll
  for (int n = 0; n < 4; ++n) {
    const int j = col0 + n * 16 + l15;
    const float bv = bias[j];
#pragma unroll
    for (int m = 0; m < 4; ++m)
#pragma unroll
      for (int r = 0; r < 4; ++r)
        C[(size_t)(rb + m * 16 + r) * NMAT + j] = acc[m][n][r] + bv;
  }
#undef STAGE
#undef WAITBAR
#undef PBAR
}

extern "C" void kernel_launch(void* const* d_in, const int* in_sizes, int n_in,
                              void* d_out, int out_size, void* d_ws, size_t ws_size,
                              hipStream_t stream) {
  const float* x  = (const float*)d_in[0];
  const float* w  = (const float*)d_in[1];
  const float* bs = (const float*)d_in[2];
  float* out = (float*)d_out;

  uint2* xd = (uint2*)d_ws;                       // 2048x2048 bf16 = 8MB
  uint2* wd = xd + (NMAT * (size_t)NMAT / 4);     // next 8MB

  qdq_kernel<<<dim3(8192), dim3(256), 0, stream>>>(x, xd, w, wd);

  gemm_kernel<<<dim3(512), dim3(128), 0, stream>>>((const __bf16*)xd,
                                                   (const __bf16*)wd, bs, out);
}